// Round 1
// baseline (863.416 us; speedup 1.0000x reference)
//
#include <hip/hip_runtime.h>
#include <hip/hip_bf16.h>

// Problem constants (from reference)
namespace {
constexpr int kB = 128, kL = 720, kF = 128;
constexpr int kSeg = 24, kWin = 15, kNPred = 4, kD = 128;
constexpr float kEps = 1e-6f;
constexpr float kMaxN = 1.0f - 1e-5f;
constexpr int kT0off = (30 - kWin) * kSeg;  // 360: only last 15 segments matter
constexpr int K1R = 8;                      // rows per K1 block
constexpr int ZS = kWin * kD + 8;           // 1928: +8-word pad -> rows offset by 8 banks
}

__device__ __forceinline__ float artanh_clip(float x) {
  float xc = fminf(x, 1.0f - 1e-7f);
  // 1-xc exact for xc in [0.5,1] (Sterbenz), safe near boundary
  return 0.5f * logf((1.0f + xc) / (1.0f - xc));
}

// ---------------- K1: stage1 GEMM + expmap0 + hyperbolic recurrence -> t0 (bf16) ----
extern "C" __global__ __launch_bounds__(256)
void mwhf_k1(const float* __restrict__ trend,
             const float* __restrict__ seas_c,
             const float* __restrict__ seas_f,
             const float* __restrict__ resid,
             const float* __restrict__ W_t, const float* __restrict__ b_t,
             const float* __restrict__ W_c, const float* __restrict__ b_c,
             const float* __restrict__ W_f, const float* __restrict__ b_f,
             const float* __restrict__ W_r, const float* __restrict__ b_r,
             const float* __restrict__ alpha,
             __hip_bfloat16* __restrict__ t0_out)
{
  __shared__ float zsh[K1R * ZS];        // 61696 B  z window, ring of 15 slots/row
  __shared__ float Wl[96 * 128];         // 49152 B  W[k= stream*24+s][d]
  __shared__ float xs[kWin * 96 * K1R];  // 46080 B  x[seg][k][fi]
  __shared__ float z2sh[K1R * kWin];     // cached sqnorm per (row, slot)
  __shared__ float bsum[128];

  const int tid = threadIdx.x;
  const int row0 = blockIdx.x * K1R;     // global row = b*128 + f
  const int bb = row0 / kF;
  const int f0 = row0 % kF;

  // stage W (fp32) and summed bias
  for (int e = tid; e < 24 * 128; e += 256) {
    Wl[e]          = W_t[e];
    Wl[24*128 + e] = W_c[e];
    Wl[48*128 + e] = W_f[e];
    Wl[72*128 + e] = W_r[e];
  }
  if (tid < 128) bsum[tid] = b_t[tid] + b_c[tid] + b_f[tid] + b_r[tid];

  // stage x: xs[seg][k][fi], k = stream*24 + s  (only last 15 segments of L)
  {
    const float* ptrs[4] = {trend, seas_c, seas_f, resid};
#pragma unroll
    for (int st = 0; st < 4; ++st) {
      const float* p = ptrs[st];
      for (int e = tid; e < kWin * 24 * K1R; e += 256) {
        int fi = e & 7;
        int s = (e >> 3) % 24;
        int seg = e / (24 * 8);
        xs[seg * (96 * 8) + (st * 24 + s) * 8 + fi] =
            p[(size_t)(bb * kL + kT0off + seg * kSeg + s) * kF + f0 + fi];
      }
    }
  }
  __syncthreads();

  // ---- stage 1: tan = x @ W + bsum, then z = project(expmap0(tan)) into zsh ----
  {
    const int seg = tid >> 4;   // 0..15 (seg 15 idle)
    const int dg = tid & 15;    // d = dg*8 .. dg*8+7
    if (seg < kWin) {
      float acc[8][8];
#pragma unroll
      for (int r = 0; r < 8; ++r)
#pragma unroll
        for (int j = 0; j < 8; ++j) acc[r][j] = 0.f;

      const float* xrow = &xs[seg * (96 * 8)];
      const float* wcol = &Wl[dg * 8];
#pragma unroll 4
      for (int k = 0; k < 96; ++k) {
        float x8[8], w8[8];
        *(float4*)&x8[0] = *(const float4*)&xrow[k * 8];
        *(float4*)&x8[4] = *(const float4*)&xrow[k * 8 + 4];
        *(float4*)&w8[0] = *(const float4*)&wcol[k * 128];
        *(float4*)&w8[4] = *(const float4*)&wcol[k * 128 + 4];
#pragma unroll
        for (int r = 0; r < 8; ++r)
#pragma unroll
          for (int j = 0; j < 8; ++j) acc[r][j] += x8[r] * w8[j];
      }
      float bv[8];
      *(float4*)&bv[0] = *(const float4*)&bsum[dg * 8];
      *(float4*)&bv[4] = *(const float4*)&bsum[dg * 8 + 4];
#pragma unroll
      for (int r = 0; r < 8; ++r) {
#pragma unroll
        for (int j = 0; j < 8; ++j) acc[r][j] += bv[j];
        // expmap0 + project (reduction over the 16 lanes holding this seg)
        float part = 0.f;
#pragma unroll
        for (int j = 0; j < 8; ++j) part += acc[r][j] * acc[r][j];
#pragma unroll
        for (int m = 1; m <= 8; m <<= 1) part += __shfl_xor(part, m, 64);
        float v2 = part;
        float nv = sqrtf(fmaxf(v2, 1e-12f));
        float th = tanhf(nv);
        float sc = th / nv;
        float y2 = sc * sc * v2;
        float yn = sqrtf(fmaxf(y2, 1e-12f));
        float proj = (yn > kMaxN) ? (kMaxN / yn) : 1.0f;
        float scale = sc * proj;
        float zz2 = y2 * proj * proj;
        float o8[8];
#pragma unroll
        for (int j = 0; j < 8; ++j) o8[j] = acc[r][j] * scale;
        float* zp = &zsh[r * ZS + seg * kD + dg * 8];
        *(float4*)&zp[0] = *(const float4*)&o8[0];
        *(float4*)&zp[4] = *(const float4*)&o8[4];
        if (dg == 0) z2sh[r * kWin + seg] = zz2;
      }
    }
  }
  __syncthreads();

  // ---- recurrence: 4 iterations, per-row in one 32-lane group (no barriers) ----
  {
    const int row = tid >> 5;   // 0..7
    const int l32 = tid & 31;   // 4 d-components per lane
    float* zr = &zsh[row * ZS];
    float* z2r = &z2sh[row * kWin];
    const float alp = alpha[0];

    float w14[14];
    w14[13] = 1.f;
#pragma unroll
    for (int i = 12; i >= 0; --i) w14[i] = w14[i + 1] * 0.9f;
    float ssum = 0.f;
#pragma unroll
    for (int i = 0; i < 14; ++i) ssum += w14[i];
    float winv = 1.f / ssum;
#pragma unroll
    for (int i = 0; i < 14; ++i) w14[i] *= winv;

    for (int it = 0; it < kNPred; ++it) {
      float avx = 0.f, avy = 0.f, avz = 0.f, avw = 0.f;
#pragma unroll
      for (int i = 0; i < 14; ++i) {
        int pa = it + i;     if (pa >= kWin) pa -= kWin;
        int pb = pa + 1;     if (pb >= kWin) pb -= kWin;
        float4 xv = *(const float4*)&zr[pa * kD + l32 * 4];
        float4 yv = *(const float4*)&zr[pb * kD + l32 * 4];
        float x2 = z2r[pa];
        float y2 = z2r[pb];
        float dp = xv.x * yv.x + xv.y * yv.y + xv.z * yv.z + xv.w * yv.w;
#pragma unroll
        for (int m = 1; m <= 16; m <<= 1) dp += __shfl_xor(dp, m, 64);
        // vel = logmap(x, y):  d = mobius_add(-x, y) = (A*(-x) + Bq*y)/den
        float A = 1.f - 2.f * dp + y2;
        float Bq = 1.f - x2;
        float den = fmaxf(1.f - 2.f * dp + x2 * y2, kEps);
        float invd = 1.f / den;
        // analytic ||d||^2 avoids a second reduction
        float d2 = (A * A * x2 - 2.f * A * Bq * dp + Bq * Bq * y2) * invd * invd;
        float n = sqrtf(fmaxf(d2, 1e-12f));
        float coef = fmaxf(1.f - x2, kEps) * artanh_clip(n) / n;  // (2/lam)*artanh(n)/n
        float wi = w14[i] * coef * invd;
        avx += wi * (Bq * yv.x - A * xv.x);
        avy += wi * (Bq * yv.y - A * xv.y);
        avz += wi * (Bq * yv.z - A * xv.z);
        avw += wi * (Bq * yv.w - A * xv.w);
      }
      // z_next = project(mobius_add(z_last, tanh(lam*|v|/2)*v/|v|))
      float vx = alp * avx, vy = alp * avy, vz = alp * avz, vw = alp * avw;
      int pl = it + 14; if (pl >= kWin) pl -= kWin;
      float4 xl = *(const float4*)&zr[pl * kD + l32 * 4];
      float x2l = z2r[pl];
      float v2 = vx * vx + vy * vy + vz * vz + vw * vw;
      float xdv = xl.x * vx + xl.y * vy + xl.z * vz + xl.w * vw;
#pragma unroll
      for (int m = 1; m <= 16; m <<= 1) {
        v2 += __shfl_xor(v2, m, 64);
        xdv += __shfl_xor(xdv, m, 64);
      }
      float nv = sqrtf(fmaxf(v2, 1e-12f));
      float lam = 2.f / fmaxf(1.f - x2l, kEps);
      float co = tanhf(0.5f * lam * nv) / nv;
      float s2 = co * co * v2;
      float xy = co * xdv;
      float P = 1.f + 2.f * xy + s2;
      float Q = 1.f - x2l;
      float den = fmaxf(1.f + 2.f * xy + x2l * s2, kEps);
      float invd = 1.f / den;
      float znx = (P * xl.x + Q * co * vx) * invd;
      float zny = (P * xl.y + Q * co * vy) * invd;
      float znz = (P * xl.z + Q * co * vz) * invd;
      float znw = (P * xl.w + Q * co * vw) * invd;
      float zn2 = (P * P * x2l + 2.f * P * Q * xy + Q * Q * s2) * invd * invd;
      float yn = sqrtf(fmaxf(zn2, 1e-12f));
      float proj = (yn > kMaxN) ? (kMaxN / yn) : 1.f;
      znx *= proj; zny *= proj; znz *= proj; znw *= proj;
      zn2 *= proj * proj;
      // append into ring (slot `it` was consumed above; same-wave lockstep, no barrier)
      float* zw = &zr[it * kD + l32 * 4];
      zw[0] = znx; zw[1] = zny; zw[2] = znz; zw[3] = znw;
      if (l32 == 0) z2r[it] = zn2;
      // t0 = logmap0(z_next) -> ws (bf16), m = row_global*4 + it
      float n0 = sqrtf(fmaxf(zn2, 1e-12f));
      float fac = artanh_clip(n0) / n0;
      __hip_bfloat16* dst = t0_out + ((size_t)(row0 + row) * 4 + it) * kD + l32 * 4;
      dst[0] = __float2bfloat16(fac * znx);
      dst[1] = __float2bfloat16(fac * zny);
      dst[2] = __float2bfloat16(fac * znz);
      dst[3] = __float2bfloat16(fac * znw);
    }
  }
}

// ---------------- K2: fused MLP  out = relu(t0@W1+b1)@W2+b2, scattered to (b,96,f) ---
extern "C" __global__ __launch_bounds__(256)
void mwhf_k2(const __hip_bfloat16* __restrict__ t0,
             const float* __restrict__ W1, const float* __restrict__ b1,
             const float* __restrict__ W2, const float* __restrict__ b2,
             float* __restrict__ outp)
{
  // region layout (union): phase A: At[128][68] (34816) + W1c[32][264] (33792)
  //                        phase B: W2l[512][28] (57344) + red[256][24] (24576)
  // hid[64][512] bf16 xor-swizzled at +81920
  __shared__ __align__(16) char smem[81920 + 65536];
  float* At  = (float*)smem;
  float* W1c = (float*)(smem + 34816);
  float* W2l = (float*)smem;
  float* red = (float*)(smem + 57344);
  __hip_bfloat16* hid = (__hip_bfloat16*)(smem + 81920);

  const int tid = threadIdx.x;
  const int m0 = blockIdx.x * 64;   // m = row_global*4 + it

  // stage A tile transposed: At[k][i] (fp32)
  for (int e = tid; e < 64 * 128; e += 256) {
    int i = e >> 7, k = e & 127;
    At[k * 68 + i] = __bfloat162float(t0[(size_t)(m0 + i) * 128 + k]);
  }

  const int rg = tid >> 5;   // 8 row-groups of 8 rows
  const int ng = tid & 31;   // 32 n-groups of 8

  for (int nh = 0; nh < 2; ++nh) {
    float acc[8][8];
#pragma unroll
    for (int r = 0; r < 8; ++r)
#pragma unroll
      for (int j = 0; j < 8; ++j) acc[r][j] = 0.f;

    for (int kc = 0; kc < 4; ++kc) {
      __syncthreads();   // also covers At staging visibility at nh=0,kc=0
      for (int e = tid; e < 32 * 256; e += 256) {
        int kk = e >> 8, n = e & 255;
        W1c[kk * 264 + n] = W1[(size_t)(kc * 32 + kk) * 512 + nh * 256 + n];
      }
      __syncthreads();
#pragma unroll 4
      for (int kk = 0; kk < 32; ++kk) {
        float a8[8], w8[8];
        const float* ap = &At[(kc * 32 + kk) * 68 + rg * 8];
        const float* wp = &W1c[kk * 264 + ng * 8];
        *(float4*)&a8[0] = *(const float4*)&ap[0];
        *(float4*)&a8[4] = *(const float4*)&ap[4];
        *(float4*)&w8[0] = *(const float4*)&wp[0];
        *(float4*)&w8[4] = *(const float4*)&wp[4];
#pragma unroll
        for (int r = 0; r < 8; ++r)
#pragma unroll
          for (int j = 0; j < 8; ++j) acc[r][j] += a8[r] * w8[j];
      }
    }
    // bias + relu -> hid (bf16, xor-swizzled so K-major reads are conflict-free)
    float b8[8];
#pragma unroll
    for (int j = 0; j < 8; ++j) b8[j] = b1[nh * 256 + ng * 8 + j];
#pragma unroll
    for (int r = 0; r < 8; ++r) {
      int i = rg * 8 + r;
      int swz = (i & 31) << 1;
#pragma unroll
      for (int j = 0; j < 8; ++j) {
        float h = fmaxf(acc[r][j] + b8[j], 0.f);
        int n = nh * 256 + ng * 8 + j;
        hid[i * 512 + (n ^ swz)] = __float2bfloat16(h);
      }
    }
  }
  __syncthreads();   // all At/W1c reads done; hid complete

  // stage W2 fp32 (overwrites At/W1c region)
  for (int e = tid; e < 512 * 24; e += 256) {
    int k = e / 24, p = e - k * 24;
    W2l[k * 28 + p] = W2[e];
  }
  __syncthreads();

  // GEMM2: K=512 split across the 4 waves; W2 rows broadcast (wave-uniform address)
  {
    const int kq = tid >> 6;      // wave id = K quarter
    const int rowi = tid & 63;
    const int swz = (rowi & 31) << 1;
    float p24[24];
#pragma unroll
    for (int p = 0; p < 24; ++p) p24[p] = 0.f;
    const int kbase = kq * 128;
    for (int k = kbase; k < kbase + 128; ++k) {
      float hv = __bfloat162float(hid[rowi * 512 + (k ^ swz)]);
      const float* wr = &W2l[k * 28];
      float w24[24];
#pragma unroll
      for (int q = 0; q < 6; ++q)
        *(float4*)&w24[q * 4] = *(const float4*)&wr[q * 4];
#pragma unroll
      for (int p = 0; p < 24; ++p) p24[p] += hv * w24[p];
    }
    float* rp = &red[(rowi * 4 + kq) * 24];
#pragma unroll
    for (int q = 0; q < 6; ++q)
      *(float4*)&rp[q * 4] = *(const float4*)&p24[q * 4];
  }
  __syncthreads();

  // combine K-quarters + b2, scatter to out[b][it*24+p][f] (16 consecutive f per write-run)
  {
    const int b = m0 >> 9;               // m0/512
    const int f0 = (m0 >> 2) & 127;
    for (int e = tid; e < 1536; e += 256) {
      int fvar = e & 15;
      int rest = e >> 4;                 // it*24 + p
      int p = rest % 24;
      int it = rest / 24;
      int i = fvar * 4 + it;             // local m index
      float s = red[(i * 4 + 0) * 24 + p] + red[(i * 4 + 1) * 24 + p]
              + red[(i * 4 + 2) * 24 + p] + red[(i * 4 + 3) * 24 + p] + b2[p];
      outp[(size_t)b * (96 * 128) + rest * 128 + f0 + fvar] = s;
    }
  }
}

extern "C" void kernel_launch(void* const* d_in, const int* in_sizes, int n_in,
                              void* d_out, int out_size, void* d_ws, size_t ws_size,
                              hipStream_t stream) {
  (void)in_sizes; (void)n_in; (void)out_size; (void)ws_size;
  const float* trend = (const float*)d_in[0];
  const float* sc    = (const float*)d_in[1];
  const float* sf    = (const float*)d_in[2];
  const float* rs    = (const float*)d_in[3];
  const float* W_t   = (const float*)d_in[4];
  const float* b_t   = (const float*)d_in[5];
  const float* W_c   = (const float*)d_in[6];
  const float* b_c   = (const float*)d_in[7];
  const float* W_f   = (const float*)d_in[8];
  const float* b_f   = (const float*)d_in[9];
  const float* W_r   = (const float*)d_in[10];
  const float* b_r   = (const float*)d_in[11];
  const float* alpha = (const float*)d_in[12];
  const float* W1    = (const float*)d_in[13];
  const float* b1    = (const float*)d_in[14];
  const float* W2    = (const float*)d_in[15];
  const float* b2    = (const float*)d_in[16];

  // workspace: t0 (logmap0 latents) as bf16, 16384*4*128*2 = 16 MiB
  __hip_bfloat16* t0 = (__hip_bfloat16*)d_ws;
  float* outp = (float*)d_out;

  hipLaunchKernelGGL(mwhf_k1, dim3(16384 / K1R), dim3(256), 0, stream,
                     trend, sc, sf, rs, W_t, b_t, W_c, b_c, W_f, b_f, W_r, b_r,
                     alpha, t0);
  hipLaunchKernelGGL(mwhf_k2, dim3(16384 * 4 / 64), dim3(256), 0, stream,
                     t0, W1, b1, W2, b2, outp);
}

// Round 2
// 577.065 us; speedup vs baseline: 1.4962x; 1.4962x over previous
//
#include <hip/hip_runtime.h>
#include <hip/hip_bf16.h>

namespace {
constexpr int kL = 720, kF = 128;
constexpr int kWin = 15, kNPred = 4;
constexpr float kEps = 1e-6f;
constexpr float kMaxN = 1.0f - 1e-5f;
constexpr int kT0off = 360;        // (30-15)*24: only last 15 segments matter
constexpr int XROW = 388;          // xs seg-row stride (floats), +4 pad kills 4-way bank conflict
constexpr int ZROW = 1928;         // zsh row stride (floats): 15*128 + 8
}

typedef float f32x4 __attribute__((ext_vector_type(4)));
typedef short s16x8 __attribute__((ext_vector_type(8)));

__device__ __forceinline__ float artanh_clip(float x) {
  float xc = fminf(x, 1.0f - 1e-7f);
  return 0.5f * logf((1.0f + xc) / (1.0f - xc));
}

// ---------- prep: W1 -> bf16 [n=512][k=128]; W2 -> bf16 [p=32 zero-padded][k=512] ----------
extern "C" __global__ __launch_bounds__(256)
void mwhf_prep(const float* __restrict__ W1, const float* __restrict__ W2,
               __hip_bfloat16* __restrict__ W1bf, __hip_bfloat16* __restrict__ W2bf)
{
  const int b = blockIdx.x, tid = threadIdx.x;
  if (b < 64) {                       // W1 [128k][512n] -> W1bf[n][k]
    const int n0 = b * 8;
    for (int e = tid; e < 1024; e += 256) {
      int n_l = e & 7, k = e >> 3;
      W1bf[(size_t)(n0 + n_l) * 128 + k] = __float2bfloat16(W1[(size_t)k * 512 + n0 + n_l]);
    }
  } else {                            // W2 [512k][24p] -> W2bf[p][k], rows 24..31 zero
    const int k0 = (b - 64) * 128;
    for (int e = tid; e < 4096; e += 256) {
      int p = e >> 7, k_l = e & 127;
      float v = (p < 24) ? W2[(size_t)(k0 + k_l) * 24 + p] : 0.0f;
      W2bf[(size_t)p * 512 + k0 + k_l] = __float2bfloat16(v);
    }
  }
}

// ---------- K1: stage1 fp32 GEMM + expmap0 + hyperbolic recurrence -> t0 (bf16) ----------
// 4 rows/block, xs unioned into zsh region (acc held in registers across barrier).
// LDS = 49152 (W) + 30848 (union) + 240 + 512 = 80752 B -> 2 blocks/CU.
extern "C" __global__ __launch_bounds__(256)
void mwhf_k1(const float* __restrict__ trend,
             const float* __restrict__ seas_c,
             const float* __restrict__ seas_f,
             const float* __restrict__ resid,
             const float* __restrict__ W_t, const float* __restrict__ b_t,
             const float* __restrict__ W_c, const float* __restrict__ b_c,
             const float* __restrict__ W_f, const float* __restrict__ b_f,
             const float* __restrict__ W_r, const float* __restrict__ b_r,
             const float* __restrict__ alpha,
             __hip_bfloat16* __restrict__ t0_out)
{
  __shared__ float Wl[96 * 128];     // W[k=stream*24+s][d]
  __shared__ float zxu[4 * ZROW];    // union: xs (15*XROW=5820 fl) lives inside; later z ring
  __shared__ float z2sh[4 * kWin];
  __shared__ float bsum[128];

  const int tid = threadIdx.x;
  const int row0 = blockIdx.x * 4;   // global row = b*128 + f
  const int bb = row0 >> 7;
  const int f0 = row0 & 127;

  for (int e = tid; e < 3072; e += 256) {
    Wl[e]        = W_t[e];
    Wl[3072 + e] = W_c[e];
    Wl[6144 + e] = W_f[e];
    Wl[9216 + e] = W_r[e];
  }
  if (tid < 128) bsum[tid] = b_t[tid] + b_c[tid] + b_f[tid] + b_r[tid];

  // xs[seg][k=st*24+s][fi 0..3] (float4 per (seg,k))
  float* xs = zxu;
  {
    const float* ptrs[4] = {trend, seas_c, seas_f, resid};
    for (int e = tid; e < 1440; e += 256) {
      int seg = e / 96;
      int k = e - seg * 96;
      int st = k / 24, s = k - st * 24;
      const float* p = ptrs[st];
      float4 v = *(const float4*)&p[(size_t)(bb * kL + kT0off + seg * 24 + s) * kF + f0];
      *(float4*)&xs[seg * XROW + k * 4] = v;
    }
  }
  __syncthreads();

  // ---- phase 1: tan = x @ W + bsum; expmap0 scale factors (acc stays in registers) ----
  const int seg = tid >> 4;   // 0..15 (seg 15 idle)
  const int dg  = tid & 15;
  const bool act = (seg < kWin);
  float acc[4][8];
  float scale4[4], zz24[4];
  if (act) {
#pragma unroll
    for (int r = 0; r < 4; ++r)
#pragma unroll
      for (int j = 0; j < 8; ++j) acc[r][j] = 0.f;
    const float* xrow = &xs[seg * XROW];
    const float* wcol = &Wl[dg * 8];
#pragma unroll 4
    for (int k = 0; k < 96; ++k) {
      float4 x4 = *(const float4*)&xrow[k * 4];
      float w8[8];
      *(float4*)&w8[0] = *(const float4*)&wcol[k * 128];
      *(float4*)&w8[4] = *(const float4*)&wcol[k * 128 + 4];
#pragma unroll
      for (int j = 0; j < 8; ++j) {
        acc[0][j] += x4.x * w8[j];
        acc[1][j] += x4.y * w8[j];
        acc[2][j] += x4.z * w8[j];
        acc[3][j] += x4.w * w8[j];
      }
    }
#pragma unroll
    for (int r = 0; r < 4; ++r) {
#pragma unroll
      for (int j = 0; j < 8; ++j) acc[r][j] += bsum[dg * 8 + j];
      float part = 0.f;
#pragma unroll
      for (int j = 0; j < 8; ++j) part += acc[r][j] * acc[r][j];
#pragma unroll
      for (int m = 1; m <= 8; m <<= 1) part += __shfl_xor(part, m);
      float v2 = part;
      float nv = sqrtf(fmaxf(v2, 1e-12f));
      float th = tanhf(nv);
      float sc = th / nv;
      float y2 = sc * sc * v2;
      float yn = sqrtf(fmaxf(y2, 1e-12f));
      float proj = (yn > kMaxN) ? (kMaxN / yn) : 1.0f;
      scale4[r] = sc * proj;
      zz24[r] = y2 * proj * proj;
    }
  }
  __syncthreads();             // all xs reads complete; safe to overwrite union region
  if (act) {
#pragma unroll
    for (int r = 0; r < 4; ++r) {
      float o8[8];
#pragma unroll
      for (int j = 0; j < 8; ++j) o8[j] = acc[r][j] * scale4[r];
      float* zp = &zxu[r * ZROW + seg * 128 + dg * 8];
      *(float4*)&zp[0] = *(const float4*)&o8[0];
      *(float4*)&zp[4] = *(const float4*)&o8[4];
      if (dg == 0) z2sh[r * kWin + seg] = zz24[r];
    }
  }
  __syncthreads();

  // ---- phase 2: recurrence, one wave per row (lockstep ring, no barriers) ----
  {
    const int row = tid >> 6;
    const int l = tid & 63;          // 2 d-components per lane
    float* zr = &zxu[row * ZROW];
    float* z2r = &z2sh[row * kWin];
    const float alp = alpha[0];

    float w14[14];
    w14[13] = 1.f;
#pragma unroll
    for (int i = 12; i >= 0; --i) w14[i] = w14[i + 1] * 0.9f;
    float ssum = 0.f;
#pragma unroll
    for (int i = 0; i < 14; ++i) ssum += w14[i];
    float winv = 1.f / ssum;
#pragma unroll
    for (int i = 0; i < 14; ++i) w14[i] *= winv;

    for (int it = 0; it < kNPred; ++it) {
      float avx = 0.f, avy = 0.f;
#pragma unroll
      for (int i = 0; i < 14; ++i) {
        int pa = it + i;  if (pa >= kWin) pa -= kWin;
        int pb = pa + 1;  if (pb >= kWin) pb -= kWin;
        float2 xv = *(const float2*)&zr[pa * 128 + l * 2];
        float2 yv = *(const float2*)&zr[pb * 128 + l * 2];
        float x2 = z2r[pa];
        float y2 = z2r[pb];
        float dp = xv.x * yv.x + xv.y * yv.y;
#pragma unroll
        for (int m = 1; m <= 32; m <<= 1) dp += __shfl_xor(dp, m);
        float A = 1.f - 2.f * dp + y2;
        float Bq = 1.f - x2;
        float den = fmaxf(1.f - 2.f * dp + x2 * y2, kEps);
        float invd = 1.f / den;
        float d2 = (A * A * x2 - 2.f * A * Bq * dp + Bq * Bq * y2) * invd * invd;
        float n = sqrtf(fmaxf(d2, 1e-12f));
        float coef = fmaxf(1.f - x2, kEps) * artanh_clip(n) / n;
        float wi = w14[i] * coef * invd;
        avx += wi * (Bq * yv.x - A * xv.x);
        avy += wi * (Bq * yv.y - A * xv.y);
      }
      float vx = alp * avx, vy = alp * avy;
      int pl = it + 14; if (pl >= kWin) pl -= kWin;
      float2 xl = *(const float2*)&zr[pl * 128 + l * 2];
      float x2l = z2r[pl];
      float v2 = vx * vx + vy * vy;
      float xdv = xl.x * vx + xl.y * vy;
#pragma unroll
      for (int m = 1; m <= 32; m <<= 1) {
        v2 += __shfl_xor(v2, m);
        xdv += __shfl_xor(xdv, m);
      }
      float nv = sqrtf(fmaxf(v2, 1e-12f));
      float lam = 2.f / fmaxf(1.f - x2l, kEps);
      float co = tanhf(0.5f * lam * nv) / nv;
      float s2 = co * co * v2;
      float xy = co * xdv;
      float P = 1.f + 2.f * xy + s2;
      float Q = 1.f - x2l;
      float den = fmaxf(1.f + 2.f * xy + x2l * s2, kEps);
      float invd = 1.f / den;
      float znx = (P * xl.x + Q * co * vx) * invd;
      float zny = (P * xl.y + Q * co * vy) * invd;
      float zn2 = (P * P * x2l + 2.f * P * Q * xy + Q * Q * s2) * invd * invd;
      float yn = sqrtf(fmaxf(zn2, 1e-12f));
      float proj = (yn > kMaxN) ? (kMaxN / yn) : 1.f;
      znx *= proj; zny *= proj;
      zn2 *= proj * proj;
      zr[it * 128 + l * 2] = znx;
      zr[it * 128 + l * 2 + 1] = zny;
      if (l == 0) z2r[it] = zn2;
      float n0 = sqrtf(fmaxf(zn2, 1e-12f));
      float fac = artanh_clip(n0) / n0;
      __hip_bfloat16* dst = t0_out + ((size_t)(row0 + row) * 4 + it) * 128 + l * 2;
      dst[0] = __float2bfloat16(fac * znx);
      dst[1] = __float2bfloat16(fac * zny);
    }
  }
}

// ---------- K2: fused MLP via bf16 MFMA: out = relu(t0@W1+b1)@W2+b2, scatter ----------
// LDS: A 16K | W1half 64K (union: W2 32K + red) | hid 64K = 144 KB.
extern "C" __global__ __launch_bounds__(256)
void mwhf_k2(const __hip_bfloat16* __restrict__ t0g,
             const __hip_bfloat16* __restrict__ W1bf,
             const __hip_bfloat16* __restrict__ W2bf,
             const float* __restrict__ b1, const float* __restrict__ b2,
             float* __restrict__ outp)
{
  __shared__ __align__(16) char smem[147456];
  s16x8* Av   = (s16x8*)smem;               // A [64 m][16 chunks] swz: c ^ (m&7)
  s16x8* W1v  = (s16x8*)(smem + 16384);     // [256 n][16 chunks] swz: c ^ (n&7)
  s16x8* W2v  = (s16x8*)(smem + 16384);     // phase B: [32 p][64 chunks] swz: c ^ (p&7)
  float* red  = (float*)(smem + 49152);     // [64][25]
  __hip_bfloat16* hid = (__hip_bfloat16*)(smem + 81920);  // [64 m][512 n] swz on n
  s16x8* hidv = (s16x8*)(smem + 81920);

  const int tid = threadIdx.x;
  const int m0 = blockIdx.x * 64;           // m = row_global*4 + it
  const int w = tid >> 6, lane = tid & 63;
  const int l16 = lane & 15, quad = lane >> 4;

  // stage A: 64 rows x 256B contiguous from t0
  {
    const s16x8* src = (const s16x8*)(t0g + (size_t)m0 * 128);
    for (int e = tid; e < 1024; e += 256) {
      int m = e >> 4, c = e & 15;
      Av[m * 16 + (c ^ (m & 7))] = src[e];
    }
  }

  f32x4 acc[4][4];
  for (int nh = 0; nh < 2; ++nh) {
    __syncthreads();   // covers A visibility (nh=0) and W1v read-completion (nh=1)
    {
      const s16x8* src = (const s16x8*)W1bf + (size_t)nh * 4096;
      for (int e = tid; e < 4096; e += 256) {
        int n = e >> 4, c = e & 15;
        W1v[n * 16 + (c ^ (n & 7))] = src[e];
      }
    }
    __syncthreads();
#pragma unroll
    for (int s = 0; s < 4; ++s)
#pragma unroll
      for (int t = 0; t < 4; ++t) acc[s][t] = (f32x4)0.f;

#pragma unroll
    for (int ks = 0; ks < 4; ++ks) {
      s16x8 a[4];
#pragma unroll
      for (int s = 0; s < 4; ++s)
        a[s] = Av[(s * 16 + l16) * 16 + ((ks * 4 + quad) ^ (l16 & 7))];
#pragma unroll
      for (int t = 0; t < 4; ++t) {
        int nl = w * 64 + t * 16 + l16;
        s16x8 bfr = W1v[nl * 16 + ((ks * 4 + quad) ^ (nl & 7))];
#pragma unroll
        for (int s = 0; s < 4; ++s)
          acc[s][t] = __builtin_amdgcn_mfma_f32_16x16x32_bf16(a[s], bfr, acc[s][t], 0, 0, 0);
      }
    }
    // epilogue: bias + relu -> hid (bf16, swizzled)
#pragma unroll
    for (int t = 0; t < 4; ++t) {
      int nabs = nh * 256 + w * 64 + t * 16 + l16;
      float bv = b1[nabs];
#pragma unroll
      for (int s = 0; s < 4; ++s)
#pragma unroll
        for (int r = 0; r < 4; ++r) {
          int m = s * 16 + quad * 4 + r;
          float h = fmaxf(acc[s][t][r] + bv, 0.f);
          hid[m * 512 + (nabs ^ ((m & 7) << 3))] = __float2bfloat16(h);
        }
    }
  }
  __syncthreads();   // hid complete; W1v region free
  // stage W2 [32][512] bf16 swizzled
  {
    const s16x8* src = (const s16x8*)W2bf;
    for (int e = tid; e < 2048; e += 256) {
      int p = e >> 6, c = e & 63;
      W2v[p * 64 + (c ^ (p & 7))] = src[e];
    }
  }
  __syncthreads();
  // GEMM2: hid(64x512) @ W2(512x24pad32), wave w -> rows w*16..+15
  {
    f32x4 a2[2];
    a2[0] = (f32x4)0.f; a2[1] = (f32x4)0.f;
    const int m = w * 16 + l16;
#pragma unroll 4
    for (int ks = 0; ks < 16; ++ks) {
      s16x8 av = hidv[m * 64 + ((ks * 4 + quad) ^ (l16 & 7))];
#pragma unroll
      for (int t = 0; t < 2; ++t) {
        s16x8 bfr = W2v[(t * 16 + l16) * 64 + ((ks * 4 + quad) ^ (l16 & 7))];
        a2[t] = __builtin_amdgcn_mfma_f32_16x16x32_bf16(av, bfr, a2[t], 0, 0, 0);
      }
    }
#pragma unroll
    for (int t = 0; t < 2; ++t)
#pragma unroll
      for (int r = 0; r < 4; ++r) {
        int p = t * 16 + l16;
        if (p < 24) red[(w * 16 + quad * 4 + r) * 25 + p] = a2[t][r];
      }
  }
  __syncthreads();
  // combine + b2, scatter to out[b][it*24+p][f] (16 consecutive f per run)
  {
    const int bb = m0 >> 9;
    const int f0 = (m0 >> 2) & 127;
    for (int e = tid; e < 1536; e += 256) {
      int fi = e & 15;
      int rest = e >> 4;               // it*24 + p
      int p = rest % 24;
      int it = rest / 24;
      outp[(size_t)bb * 12288 + rest * 128 + f0 + fi] = red[(fi * 4 + it) * 25 + p] + b2[p];
    }
  }
}

extern "C" void kernel_launch(void* const* d_in, const int* in_sizes, int n_in,
                              void* d_out, int out_size, void* d_ws, size_t ws_size,
                              hipStream_t stream) {
  (void)in_sizes; (void)n_in; (void)out_size; (void)ws_size;
  const float* trend = (const float*)d_in[0];
  const float* sc    = (const float*)d_in[1];
  const float* sf    = (const float*)d_in[2];
  const float* rs    = (const float*)d_in[3];
  const float* W_t   = (const float*)d_in[4];
  const float* b_t   = (const float*)d_in[5];
  const float* W_c   = (const float*)d_in[6];
  const float* b_c   = (const float*)d_in[7];
  const float* W_f   = (const float*)d_in[8];
  const float* b_f   = (const float*)d_in[9];
  const float* W_r   = (const float*)d_in[10];
  const float* b_r   = (const float*)d_in[11];
  const float* alpha = (const float*)d_in[12];
  const float* W1    = (const float*)d_in[13];
  const float* b1    = (const float*)d_in[14];
  const float* W2    = (const float*)d_in[15];
  const float* b2    = (const float*)d_in[16];

  // ws: t0 16 MiB | W1bf 128 KiB | W2bf 32 KiB
  __hip_bfloat16* t0   = (__hip_bfloat16*)d_ws;
  __hip_bfloat16* W1bf = (__hip_bfloat16*)((char*)d_ws + 16777216);
  __hip_bfloat16* W2bf = (__hip_bfloat16*)((char*)d_ws + 16777216 + 131072);
  float* outp = (float*)d_out;

  hipLaunchKernelGGL(mwhf_prep, dim3(68), dim3(256), 0, stream, W1, W2, W1bf, W2bf);
  hipLaunchKernelGGL(mwhf_k1, dim3(4096), dim3(256), 0, stream,
                     trend, sc, sf, rs, W_t, b_t, W_c, b_c, W_f, b_f, W_r, b_r,
                     alpha, t0);
  hipLaunchKernelGGL(mwhf_k2, dim3(1024), dim3(256), 0, stream,
                     t0, W1bf, W2bf, b1, b2, outp);
}

// Round 3
// 390.819 us; speedup vs baseline: 2.2092x; 1.4766x over previous
//
#include <hip/hip_runtime.h>
#include <hip/hip_bf16.h>

namespace {
constexpr int kL = 720, kF = 128;
constexpr int kWin = 15;
constexpr float kEps = 1e-6f;
constexpr float kMaxN = 1.0f - 1e-5f;
constexpr int kT0off = 360;   // (30-15)*24: only last 15 segments matter
constexpr int XROW = 388;     // xs seg-row stride (floats)
constexpr int ZTR = 132;      // zt row stride (floats), +4 pad
// ws offsets
constexpr size_t kOffT0   = 0;                    // 16 MiB bf16 t0
constexpr size_t kOffW1   = 16777216;             // 128 KiB bf16 W1 [n][k]
constexpr size_t kOffW2   = kOffW1 + 131072;      // 32 KiB bf16 W2 [p][k]
constexpr size_t kOffWcat = kOffW2 + 32768;       // 48 KiB fp32 Wcat [96][128]
constexpr size_t kOffBsum = kOffWcat + 49152;     // 512 B fp32
constexpr size_t kOffHid  = 17825792;             // 64 MiB bf16 hid [65536][512]
constexpr size_t kWsSplit = kOffHid + 67108864;   // required for split path
}

typedef float f32x4 __attribute__((ext_vector_type(4)));
typedef short s16x8 __attribute__((ext_vector_type(8)));

__device__ __forceinline__ float rcp_f(float x) { return __builtin_amdgcn_rcpf(x); }
__device__ __forceinline__ float sqrt_f(float x) { return __builtin_amdgcn_sqrtf(x); }
__device__ __forceinline__ float tanh_f(float x) {          // x >= 0
  float t = __builtin_amdgcn_exp2f(x * -2.8853900817779268f);
  return (1.0f - t) * rcp_f(1.0f + t);
}
__device__ __forceinline__ float artanh_f(float n) {        // n >= 0
  float nc = fminf(n, 1.0f - 1e-7f);
  return 0.34657359027997264f * __builtin_amdgcn_logf((1.0f + nc) * rcp_f(1.0f - nc));
}

// ---------------- prep: weight repack (bf16 + Wcat + bsum) ----------------
extern "C" __global__ __launch_bounds__(256)
void mwhf_prep(const float* __restrict__ W1, const float* __restrict__ W2,
               const float* __restrict__ W_t, const float* __restrict__ W_c,
               const float* __restrict__ W_f, const float* __restrict__ W_r,
               const float* __restrict__ b_t, const float* __restrict__ b_c,
               const float* __restrict__ b_f, const float* __restrict__ b_r,
               __hip_bfloat16* __restrict__ W1bf, __hip_bfloat16* __restrict__ W2bf,
               float* __restrict__ Wcat, float* __restrict__ bsum)
{
  const int b = blockIdx.x, tid = threadIdx.x;
  if (b < 64) {                       // W1 [128k][512n] -> W1bf[n][k]
    const int n0 = b * 8;
    for (int e = tid; e < 1024; e += 256) {
      int n_l = e & 7, k = e >> 3;
      W1bf[(size_t)(n0 + n_l) * 128 + k] = __float2bfloat16(W1[(size_t)k * 512 + n0 + n_l]);
    }
  } else if (b < 68) {                // W2 [512k][24p] -> W2bf[p][k], rows 24..31 zero
    const int k0 = (b - 64) * 128;
    for (int e = tid; e < 4096; e += 256) {
      int p = e >> 7, k_l = e & 127;
      float v = (p < 24) ? W2[(size_t)(k0 + k_l) * 24 + p] : 0.0f;
      W2bf[(size_t)p * 512 + k0 + k_l] = __float2bfloat16(v);
    }
  } else if (b < 72) {                // Wcat[st*24+s][d]
    const int st = b - 68;
    const float* src = (st == 0) ? W_t : (st == 1) ? W_c : (st == 2) ? W_f : W_r;
    for (int e = tid; e < 3072; e += 256) Wcat[st * 3072 + e] = src[e];
  } else {
    if (tid < 128) bsum[tid] = b_t[tid] + b_c[tid] + b_f[tid] + b_r[tid];
  }
}

// ---------------- K1: stage1 GEMM(fp32, W streamed) + expmap0 + recurrence -> t0 ----
// LDS ~31.9 KB; z-ring in registers; batched reductions; analytic pair-dp append.
extern "C" __global__ __launch_bounds__(256, 4)
void mwhf_k1(const float* __restrict__ trend,
             const float* __restrict__ seas_c,
             const float* __restrict__ seas_f,
             const float* __restrict__ resid,
             const float* __restrict__ Wcat, const float* __restrict__ bsum,
             const float* __restrict__ alpha,
             __hip_bfloat16* __restrict__ t0_out)
{
  __shared__ float ublk[4 * kWin * ZTR];   // 31680 B: xs (5820 fl) unioned with zt
  __shared__ float z2t[64];                // [r][seg] (4x16)

  const int tid = threadIdx.x;
  // XCD-aware swizzle: group the 32 f-sibling blocks of a batch row per XCD
  const int bix = blockIdx.x;
  const int bb = (bix & 7) * 16 + (bix >> 8);
  const int f0 = ((bix >> 3) & 31) * 4;
  const int row0 = bb * 128 + f0;

  // stage xs[seg][k=st*24+s] (float4 of features f0..f0+3)
  {
    float* xs = ublk;
    const float* ptrs[4] = {trend, seas_c, seas_f, resid};
    for (int e = tid; e < 1440; e += 256) {
      int seg = e / 96;
      int k = e - seg * 96;
      int st = k / 24, s = k - st * 24;
      const float* p = ptrs[st];
      float4 v = *(const float4*)&p[(size_t)(bb * kL + kT0off + seg * 24 + s) * kF + f0];
      *(float4*)&ublk[seg * XROW + k * 4] = v;
      (void)xs;
    }
  }
  __syncthreads();

  // ---- phase 1: tan = x @ Wcat + bsum; expmap0 (acc in registers across barrier) ----
  const int seg = tid >> 4;   // 0..15 (seg 15 idle)
  const int dg  = tid & 15;
  const bool act = (seg < kWin);
  float acc[4][8];
  float scale4[4], zz24[4];
  if (act) {
#pragma unroll
    for (int r = 0; r < 4; ++r)
#pragma unroll
      for (int j = 0; j < 8; ++j) acc[r][j] = 0.f;
    const float* xrow = &ublk[seg * XROW];
    const float* wp = Wcat + dg * 8;
#pragma unroll 4
    for (int k = 0; k < 96; ++k) {
      float4 x4 = *(const float4*)&xrow[k * 4];
      float4 wa = *(const float4*)&wp[k * 128];
      float4 wb = *(const float4*)&wp[k * 128 + 4];
      float w8[8] = {wa.x, wa.y, wa.z, wa.w, wb.x, wb.y, wb.z, wb.w};
#pragma unroll
      for (int j = 0; j < 8; ++j) {
        acc[0][j] += x4.x * w8[j];
        acc[1][j] += x4.y * w8[j];
        acc[2][j] += x4.z * w8[j];
        acc[3][j] += x4.w * w8[j];
      }
    }
    float b8[8];
    *(float4*)&b8[0] = *(const float4*)&bsum[dg * 8];
    *(float4*)&b8[4] = *(const float4*)&bsum[dg * 8 + 4];
    float part[4];
#pragma unroll
    for (int r = 0; r < 4; ++r) {
      part[r] = 0.f;
#pragma unroll
      for (int j = 0; j < 8; ++j) {
        acc[r][j] += b8[j];
        part[r] += acc[r][j] * acc[r][j];
      }
    }
#pragma unroll
    for (int m = 1; m <= 8; m <<= 1)
#pragma unroll
      for (int r = 0; r < 4; ++r) part[r] += __shfl_xor(part[r], m);
#pragma unroll
    for (int r = 0; r < 4; ++r) {
      float v2 = part[r];
      float nv = sqrt_f(fmaxf(v2, 1e-12f));
      float sc = tanh_f(nv) * rcp_f(nv);
      float y2 = sc * sc * v2;
      float yn = sqrt_f(fmaxf(y2, 1e-12f));
      float proj = (yn > kMaxN) ? (kMaxN * rcp_f(yn)) : 1.0f;
      scale4[r] = sc * proj;
      zz24[r] = y2 * proj * proj;
    }
  }
  __syncthreads();             // xs reads complete -> overwrite union with zt
  if (act) {
#pragma unroll
    for (int r = 0; r < 4; ++r) {
      float o8[8];
#pragma unroll
      for (int j = 0; j < 8; ++j) o8[j] = acc[r][j] * scale4[r];
      float* zp = &ublk[(r * kWin + seg) * ZTR + dg * 8];
      *(float4*)&zp[0] = *(const float4*)&o8[0];
      *(float4*)&zp[4] = *(const float4*)&o8[4];
      if (dg == 0) z2t[r * 16 + seg] = zz24[r];
    }
  }
  __syncthreads();

  // ---- phase 2: recurrence entirely in registers; wave w handles row row0+w ----
  {
    const int w = tid >> 6;
    const int l = tid & 63;          // components 2l, 2l+1
    float zx[19], zy[19], z2a[19], pd[18];
#pragma unroll
    for (int j = 0; j < 15; ++j) {
      float2 v = *(const float2*)&ublk[(w * kWin + j) * ZTR + 2 * l];
      zx[j] = v.x; zy[j] = v.y;
      z2a[j] = z2t[w * 16 + j];
    }
    // initial 14 pair dot products, batched butterfly (depth 6)
#pragma unroll
    for (int j = 0; j < 14; ++j) pd[j] = zx[j] * zx[j + 1] + zy[j] * zy[j + 1];
#pragma unroll
    for (int m = 1; m <= 32; m <<= 1)
#pragma unroll
      for (int j = 0; j < 14; ++j) pd[j] += __shfl_xor(pd[j], m);

    const float alp = alpha[0];
    float W14[14];
    {
      float wv = 1.f, ss = 0.f;
      W14[13] = 1.f;
#pragma unroll
      for (int i = 12; i >= 0; --i) { wv *= 0.9f; W14[i] = wv; }
#pragma unroll
      for (int i = 0; i < 14; ++i) ss += W14[i];
      float inv = 1.f / ss;
#pragma unroll
      for (int i = 0; i < 14; ++i) W14[i] *= inv;
    }

#pragma unroll
    for (int it = 0; it < 4; ++it) {
      float avx = 0.f, avy = 0.f;
#pragma unroll
      for (int i = 0; i < 14; ++i) {
        const int j = it + i, y = j + 1;
        float x2 = z2a[j], y2 = z2a[y], dp = pd[j];
        float A = 1.f - 2.f * dp + y2;
        float Bq = 1.f - x2;
        float den = fmaxf(1.f - 2.f * dp + x2 * y2, kEps);
        float invd = rcp_f(den);
        float d2 = (A * A * x2 - 2.f * A * Bq * dp + Bq * Bq * y2) * (invd * invd);
        float n = sqrt_f(fmaxf(d2, 1e-12f));
        float coef = fmaxf(Bq, kEps) * artanh_f(n) * rcp_f(n);
        float wi = W14[i] * coef * invd;
        avx += wi * (Bq * zx[y] - A * zx[j]);
        avy += wi * (Bq * zy[y] - A * zy[j]);
      }
      float vx = alp * avx, vy = alp * avy;
      const int pl = it + 14;
      float x2l = z2a[pl];
      float v2 = vx * vx + vy * vy;
      float xdv = zx[pl] * vx + zy[pl] * vy;
#pragma unroll
      for (int m = 1; m <= 32; m <<= 1) {
        v2 += __shfl_xor(v2, m);
        xdv += __shfl_xor(xdv, m);
      }
      float nv = sqrt_f(fmaxf(v2, 1e-12f));
      float lam = 2.f * rcp_f(fmaxf(1.f - x2l, kEps));
      float co = tanh_f(0.5f * lam * nv) * rcp_f(nv);
      float s2 = co * co * v2;
      float xy = co * xdv;
      float P = 1.f + 2.f * xy + s2;
      float Q = 1.f - x2l;
      float den2 = fmaxf(1.f + 2.f * xy + x2l * s2, kEps);
      float invd2 = rcp_f(den2);
      float znx = (P * zx[pl] + Q * co * vx) * invd2;
      float zny = (P * zy[pl] + Q * co * vy) * invd2;
      float zn2 = (P * P * x2l + 2.f * P * Q * xy + Q * Q * s2) * (invd2 * invd2);
      float pdn = (P * x2l + Q * xy) * invd2;        // <z_last, z_next_unproj>
      float yn = sqrt_f(fmaxf(zn2, 1e-12f));
      float proj = (yn > kMaxN) ? (kMaxN * rcp_f(yn)) : 1.f;
      znx *= proj; zny *= proj;
      zn2 *= proj * proj;
      pdn *= proj;
      zx[15 + it] = znx; zy[15 + it] = zny;
      z2a[15 + it] = zn2;
      pd[14 + it] = pdn;
      // t0 = logmap0(z_next)
      float n0 = sqrt_f(fmaxf(zn2, 1e-12f));
      float fac = artanh_f(n0) * rcp_f(n0);
      __hip_bfloat162 hv;
      hv.x = __float2bfloat16(fac * znx);
      hv.y = __float2bfloat16(fac * zny);
      *(__hip_bfloat162*)(t0_out + ((size_t)(row0 + w) * 4 + it) * 128 + 2 * l) = hv;
    }
  }
}

// ---------------- K2a: hid = relu(t0 @ W1 + b1), LDS-free streaming MFMA ----------------
extern "C" __global__ __launch_bounds__(256, 4)
void mwhf_k2a(const __hip_bfloat16* __restrict__ t0g,
              const __hip_bfloat16* __restrict__ W1bf,
              const float* __restrict__ b1,
              __hip_bfloat16* __restrict__ hid)
{
  const int tid = threadIdx.x;
  const int w = tid >> 6, lane = tid & 63;
  const int l16 = lane & 15, quad = lane >> 4;
  const int mbase = blockIdx.x * 32;
  const int ng = w * 128;

  s16x8 afr[2][4];
#pragma unroll
  for (int s = 0; s < 2; ++s)
#pragma unroll
    for (int kc = 0; kc < 4; ++kc)
      afr[s][kc] = *(const s16x8*)(t0g + (size_t)(mbase + s * 16 + l16) * 128 + kc * 32 + quad * 8);

  f32x4 acc[2][8];
#pragma unroll
  for (int s = 0; s < 2; ++s)
#pragma unroll
    for (int t = 0; t < 8; ++t) acc[s][t] = (f32x4)0.f;

#pragma unroll
  for (int t = 0; t < 8; ++t) {
    const __hip_bfloat16* bp = W1bf + (size_t)(ng + t * 16 + l16) * 128 + quad * 8;
#pragma unroll
    for (int kc = 0; kc < 4; ++kc) {
      s16x8 bfr = *(const s16x8*)(bp + kc * 32);
      acc[0][t] = __builtin_amdgcn_mfma_f32_16x16x32_bf16(afr[0][kc], bfr, acc[0][t], 0, 0, 0);
      acc[1][t] = __builtin_amdgcn_mfma_f32_16x16x32_bf16(afr[1][kc], bfr, acc[1][t], 0, 0, 0);
    }
  }
#pragma unroll
  for (int t = 0; t < 8; ++t) {
    const int n = ng + t * 16 + l16;
    float bv = b1[n];
#pragma unroll
    for (int s = 0; s < 2; ++s)
#pragma unroll
      for (int r = 0; r < 4; ++r) {
        int m = mbase + s * 16 + quad * 4 + r;
        float h = fmaxf(acc[s][t][r] + bv, 0.f);
        hid[(size_t)m * 512 + n] = __float2bfloat16(h);
      }
  }
}

// ---------------- K2b: out = hid @ W2 + b2, scattered to (b, 96, f) ----------------
extern "C" __global__ __launch_bounds__(256, 4)
void mwhf_k2b(const __hip_bfloat16* __restrict__ hid,
              const __hip_bfloat16* __restrict__ W2bf,
              const float* __restrict__ b2,
              float* __restrict__ outp)
{
  const int tid = threadIdx.x;
  const int w = tid >> 6, lane = tid & 63;
  const int l16 = lane & 15, quad = lane >> 4;
  const int mb = (blockIdx.x * 4 + w) * 32;

  f32x4 acc[2][2];
#pragma unroll
  for (int s = 0; s < 2; ++s)
#pragma unroll
    for (int t = 0; t < 2; ++t) acc[s][t] = (f32x4)0.f;

#pragma unroll 4
  for (int kc = 0; kc < 16; ++kc) {
    s16x8 a0 = *(const s16x8*)(hid + (size_t)(mb + l16) * 512 + kc * 32 + quad * 8);
    s16x8 a1 = *(const s16x8*)(hid + (size_t)(mb + 16 + l16) * 512 + kc * 32 + quad * 8);
#pragma unroll
    for (int t = 0; t < 2; ++t) {
      s16x8 bfr = *(const s16x8*)(W2bf + (size_t)(t * 16 + l16) * 512 + kc * 32 + quad * 8);
      acc[0][t] = __builtin_amdgcn_mfma_f32_16x16x32_bf16(a0, bfr, acc[0][t], 0, 0, 0);
      acc[1][t] = __builtin_amdgcn_mfma_f32_16x16x32_bf16(a1, bfr, acc[1][t], 0, 0, 0);
    }
  }
#pragma unroll
  for (int t = 0; t < 2; ++t) {
    const int p = t * 16 + l16;
    if (p < 24) {
      float bv = b2[p];
#pragma unroll
      for (int s = 0; s < 2; ++s)
#pragma unroll
        for (int r = 0; r < 4; ++r) {
          int m = mb + s * 16 + quad * 4 + r;
          int bbi = m >> 9, it = m & 3, f = (m >> 2) & 127;
          outp[(size_t)bbi * 12288 + (it * 24 + p) * 128 + f] = acc[s][t][r] + bv;
        }
    }
  }
}

// ---------------- fallback fused K2 (R1-verified) if ws too small for hid ----------------
extern "C" __global__ __launch_bounds__(256)
void mwhf_k2f(const __hip_bfloat16* __restrict__ t0g,
              const __hip_bfloat16* __restrict__ W1bf,
              const __hip_bfloat16* __restrict__ W2bf,
              const float* __restrict__ b1, const float* __restrict__ b2,
              float* __restrict__ outp)
{
  __shared__ __align__(16) char smem[147456];
  s16x8* Av   = (s16x8*)smem;
  s16x8* W1v  = (s16x8*)(smem + 16384);
  s16x8* W2v  = (s16x8*)(smem + 16384);
  float* red  = (float*)(smem + 49152);
  __hip_bfloat16* hid = (__hip_bfloat16*)(smem + 81920);
  s16x8* hidv = (s16x8*)(smem + 81920);

  const int tid = threadIdx.x;
  const int m0 = blockIdx.x * 64;
  const int w = tid >> 6, lane = tid & 63;
  const int l16 = lane & 15, quad = lane >> 4;

  {
    const s16x8* src = (const s16x8*)(t0g + (size_t)m0 * 128);
    for (int e = tid; e < 1024; e += 256) {
      int m = e >> 4, c = e & 15;
      Av[m * 16 + (c ^ (m & 7))] = src[e];
    }
  }
  f32x4 acc[4][4];
  for (int nh = 0; nh < 2; ++nh) {
    __syncthreads();
    {
      const s16x8* src = (const s16x8*)W1bf + (size_t)nh * 4096;
      for (int e = tid; e < 4096; e += 256) {
        int n = e >> 4, c = e & 15;
        W1v[n * 16 + (c ^ (n & 7))] = src[e];
      }
    }
    __syncthreads();
#pragma unroll
    for (int s = 0; s < 4; ++s)
#pragma unroll
      for (int t = 0; t < 4; ++t) acc[s][t] = (f32x4)0.f;
#pragma unroll
    for (int ks = 0; ks < 4; ++ks) {
      s16x8 a[4];
#pragma unroll
      for (int s = 0; s < 4; ++s)
        a[s] = Av[(s * 16 + l16) * 16 + ((ks * 4 + quad) ^ (l16 & 7))];
#pragma unroll
      for (int t = 0; t < 4; ++t) {
        int nl = w * 64 + t * 16 + l16;
        s16x8 bfr = W1v[nl * 16 + ((ks * 4 + quad) ^ (nl & 7))];
#pragma unroll
        for (int s = 0; s < 4; ++s)
          acc[s][t] = __builtin_amdgcn_mfma_f32_16x16x32_bf16(a[s], bfr, acc[s][t], 0, 0, 0);
      }
    }
#pragma unroll
    for (int t = 0; t < 4; ++t) {
      int nabs = nh * 256 + w * 64 + t * 16 + l16;
      float bv = b1[nabs];
#pragma unroll
      for (int s = 0; s < 4; ++s)
#pragma unroll
        for (int r = 0; r < 4; ++r) {
          int m = s * 16 + quad * 4 + r;
          float h = fmaxf(acc[s][t][r] + bv, 0.f);
          hid[m * 512 + (nabs ^ ((m & 7) << 3))] = __float2bfloat16(h);
        }
    }
  }
  __syncthreads();
  {
    const s16x8* src = (const s16x8*)W2bf;
    for (int e = tid; e < 2048; e += 256) {
      int p = e >> 6, c = e & 63;
      W2v[p * 64 + (c ^ (p & 7))] = src[e];
    }
  }
  __syncthreads();
  {
    f32x4 a2[2];
    a2[0] = (f32x4)0.f; a2[1] = (f32x4)0.f;
    const int m = w * 16 + l16;
#pragma unroll 4
    for (int ks = 0; ks < 16; ++ks) {
      s16x8 av = hidv[m * 64 + ((ks * 4 + quad) ^ (l16 & 7))];
#pragma unroll
      for (int t = 0; t < 2; ++t) {
        s16x8 bfr = W2v[(t * 16 + l16) * 64 + ((ks * 4 + quad) ^ (l16 & 7))];
        a2[t] = __builtin_amdgcn_mfma_f32_16x16x32_bf16(av, bfr, a2[t], 0, 0, 0);
      }
    }
#pragma unroll
    for (int t = 0; t < 2; ++t)
#pragma unroll
      for (int r = 0; r < 4; ++r) {
        int p = t * 16 + l16;
        if (p < 24) red[(w * 16 + quad * 4 + r) * 25 + p] = a2[t][r];
      }
  }
  __syncthreads();
  {
    const int bbi = m0 >> 9;
    const int f0 = (m0 >> 2) & 127;
    for (int e = tid; e < 1536; e += 256) {
      int fi = e & 15;
      int rest = e >> 4;
      int p = rest % 24;
      int it = rest / 24;
      outp[(size_t)bbi * 12288 + rest * 128 + f0 + fi] = red[(fi * 4 + it) * 25 + p] + b2[p];
    }
  }
}

extern "C" void kernel_launch(void* const* d_in, const int* in_sizes, int n_in,
                              void* d_out, int out_size, void* d_ws, size_t ws_size,
                              hipStream_t stream) {
  (void)in_sizes; (void)n_in; (void)out_size;
  const float* trend = (const float*)d_in[0];
  const float* sc    = (const float*)d_in[1];
  const float* sf    = (const float*)d_in[2];
  const float* rs    = (const float*)d_in[3];
  const float* W_t   = (const float*)d_in[4];
  const float* b_t   = (const float*)d_in[5];
  const float* W_c   = (const float*)d_in[6];
  const float* b_c   = (const float*)d_in[7];
  const float* W_f   = (const float*)d_in[8];
  const float* b_f   = (const float*)d_in[9];
  const float* W_r   = (const float*)d_in[10];
  const float* b_r   = (const float*)d_in[11];
  const float* alpha = (const float*)d_in[12];
  const float* W1    = (const float*)d_in[13];
  const float* b1    = (const float*)d_in[14];
  const float* W2    = (const float*)d_in[15];
  const float* b2    = (const float*)d_in[16];

  char* ws = (char*)d_ws;
  __hip_bfloat16* t0   = (__hip_bfloat16*)(ws + kOffT0);
  __hip_bfloat16* W1bf = (__hip_bfloat16*)(ws + kOffW1);
  __hip_bfloat16* W2bf = (__hip_bfloat16*)(ws + kOffW2);
  float* Wcat = (float*)(ws + kOffWcat);
  float* bsum = (float*)(ws + kOffBsum);
  __hip_bfloat16* hid = (__hip_bfloat16*)(ws + kOffHid);
  float* outp = (float*)d_out;

  hipLaunchKernelGGL(mwhf_prep, dim3(73), dim3(256), 0, stream,
                     W1, W2, W_t, W_c, W_f, W_r, b_t, b_c, b_f, b_r,
                     W1bf, W2bf, Wcat, bsum);
  hipLaunchKernelGGL(mwhf_k1, dim3(4096), dim3(256), 0, stream,
                     trend, sc, sf, rs, Wcat, bsum, alpha, t0);
  if (ws_size >= kWsSplit) {
    hipLaunchKernelGGL(mwhf_k2a, dim3(2048), dim3(256), 0, stream, t0, W1bf, b1, hid);
    hipLaunchKernelGGL(mwhf_k2b, dim3(512), dim3(256), 0, stream, hid, W2bf, b2, outp);
  } else {
    hipLaunchKernelGGL(mwhf_k2f, dim3(1024), dim3(256), 0, stream,
                       t0, W1bf, W2bf, b1, b2, outp);
  }
}